// Round 8
// baseline (1426.728 us; speedup 1.0000x reference)
//
#include <hip/hip_runtime.h>
#include <stdint.h>
#include <stddef.h>

#define T_   4096
#define BT_  8192
#define SCALING_F      0.04419417382415922f
#define LAMBDA_INIT_F  0.7836057665316212f
#define ONE_MINUS_LI_F 0.2163942334683788f

typedef __attribute__((ext_vector_type(8))) short short8;
typedef __attribute__((ext_vector_type(4))) short short4v;
typedef __attribute__((ext_vector_type(4))) float f32x4;

__device__ __forceinline__ short f2bf(float f){
  uint32_t u = __float_as_uint(f);
  uint32_t r = (u + 0x7fffu + ((u >> 16) & 1u)) >> 16;   // RNE
  return (short)(uint16_t)r;
}

__device__ __forceinline__ f32x4 mfma16(short8 a, short8 b, f32x4 c){
  return __builtin_amdgcn_mfma_f32_16x16x32_bf16(a, b, c, 0, 0, 0);
}

__device__ __forceinline__ void stage16(short* lds, const short* g){
  __builtin_amdgcn_global_load_lds(
      (const __attribute__((address_space(1))) void*)g,
      (__attribute__((address_space(3))) void*)lds, 16, 0, 0);
}

// ---------------- merged fp32 -> bf16 convert (7 segments) ----------------
struct CvtArgs {
  const float* src[7];
  short*       dst[7];
  int          n4[7];     // float4 count per segment
  int          total4;
};

__global__ void k_cvt(CvtArgs a){
  int i  = blockIdx.x*blockDim.x + threadIdx.x;
  int st = gridDim.x*blockDim.x;
  for (; i < a.total4; i += st){
    int seg = 0, off = i;
    #pragma unroll
    for (int s = 0; s < 6; s++){
      if (off >= a.n4[seg]){ off -= a.n4[seg]; seg++; }
    }
    float4 v = ((const float4*)a.src[seg])[off];
    short4v o;
    o.x = f2bf(v.x); o.y = f2bf(v.y); o.z = f2bf(v.z); o.w = f2bf(v.w);
    ((short4v*)a.dst[seg])[off] = o;
  }
}

// ---------------- NT GEMM: C[m][n] = sum_k A[m][k]*B[n][k], K=1024 fixed ----
// EPI: 0 = bf16 out, 1 = bf16 out * SCALING, 2 = fp32 out
template<int EPI>
__global__ __launch_bounds__(256, 3) void k_gemm(const short* __restrict__ A,
                                                 const short* __restrict__ Bm,
                                                 void* __restrict__ Cp, int ldc){
  __shared__ short As[128*32];
  __shared__ short Bs[128*32];
  const int tid = threadIdx.x;
  const int w = tid >> 6, l = tid & 63;
  const int m0 = blockIdx.x * 128;
  const int n0 = blockIdx.y * 128;
  const int wr = w >> 1, wc = w & 1;

  f32x4 acc[4][4] = {};

  const short* gA = A  + (size_t)(m0 + w*32 + (l>>2))*1024 + (l&3)*8;
  const short* gB = Bm + (size_t)(n0 + w*32 + (l>>2))*1024 + (l&3)*8;

  for (int k0 = 0; k0 < 1024; k0 += 32){
    stage16(As + w*1024,       gA + k0);
    stage16(As + w*1024 + 512, gA + 16*1024 + k0);
    stage16(Bs + w*1024,       gB + k0);
    stage16(Bs + w*1024 + 512, gB + 16*1024 + k0);
    __syncthreads();
    short8 aF[4], bF[4];
    #pragma unroll
    for (int i = 0; i < 4; i++){
      aF[i] = *(const short8*)&As[(wr*64 + i*16 + (l&15))*32 + (l>>4)*8];
      bF[i] = *(const short8*)&Bs[(wc*64 + i*16 + (l&15))*32 + (l>>4)*8];
    }
    #pragma unroll
    for (int i = 0; i < 4; i++)
      #pragma unroll
      for (int j = 0; j < 4; j++)
        acc[i][j] = mfma16(aF[i], bF[j], acc[i][j]);
    __syncthreads();
  }

  #pragma unroll
  for (int i = 0; i < 4; i++){
    #pragma unroll
    for (int j = 0; j < 4; j++){
      const size_t r0 = (size_t)m0 + wr*64 + i*16 + (l>>4)*4;
      const size_t c  = (size_t)n0 + wc*64 + j*16 + (l&15);
      #pragma unroll
      for (int rg = 0; rg < 4; rg++){
        float v = acc[i][j][rg];
        if (EPI == 2){
          ((float*)Cp)[(r0+rg)*(size_t)ldc + c] = v;
        } else {
          if (EPI == 1) v *= SCALING_F;
          ((short*)Cp)[(r0+rg)*(size_t)ldc + c] = f2bf(v);
        }
      }
    }
  }
}

// ---------------- fused dual-softmax attention + RMSNorm (v8) --------------
// t-tile 16, grid 512 (XCD-swizzled), 512 thr / 8 waves, 2 blocks/CU,
// 4 waves/SIMD @ 128 regs. acc[2][8]=64 AGPR. Q in LDS (32KB, swizzled,
// staged once). K and V streamed from L2 per iter (no K LDS, no DMA in
// loop -> barriers are pure lgkmcnt+s_barrier). Phase-1: wave = one 16x16
// S-tile (h = w&1, sc = w>>1). Phase-2: wave = 128-wide d-slice.
__global__ __launch_bounds__(512, 4) void k_attn(
    const short* __restrict__ QP, const short* __restrict__ KP,
    const short* __restrict__ VPT,
    const float* __restrict__ lq1, const float* __restrict__ lk1,
    const float* __restrict__ lq2, const float* __restrict__ lk2,
    short* __restrict__ Ab)
{
  __shared__ short Qs[16*1024];    // 32 KB, phys16Bchunk(within 512-half) = logical ^ (row&7)
  __shared__ short Pl[2][16][72];  // exp(S), 9-chunk row stride
  __shared__ float lsum[8][16];
  __shared__ float rinv[2][16];
  __shared__ float ssq[8][16];

  // XCD-aware bijective swizzle (512 % 8 == 0)
  int wg = blockIdx.x;
  wg = (wg & 7)*64 + (wg >> 3);
  const int b  = wg >> 8;
  const int t0 = (wg & 255) * 16;

  const int tid = threadIdx.x;
  const int w = tid >> 6, l = tid & 63;

  // phase-1 role: one S-tile per wave
  const int h = w & 1, sc = w >> 1;

  f32x4 acc[2][8] = {};               // [head][dc]
  float lacc[4] = {0.f,0.f,0.f,0.f};

  const short* kgp = KP  + (size_t)(b*T_ + sc*16 + (l&15))*512 + (l>>4)*8;
  const short* vbp = VPT + (size_t)(w*128 + (l&15))*BT_ + (size_t)b*T_ + (l>>4)*8;

  // swizzled-read lane constants
  const int jx = (l >> 4) ^ (l & 3);
  const int kx = (l >> 2) & 1;

  // ---- prologue: stage Q (16 rows x 1024, swizzled), once ----
  {
    const short* qsrc = QP + (size_t)(b*T_ + t0)*1024;
    #pragma unroll
    for (int j = 0; j < 2; j++){
      int r = w*2 + j;
      #pragma unroll
      for (int h2 = 0; h2 < 2; h2++)
        stage16(&Qs[r*1024 + h2*512],
                qsrc + (size_t)r*1024 + (h2*64 + (l ^ (r & 7)))*8);
    }
  }
  __syncthreads();

  const short* qp0 = &Qs[(l&15)*1024 + h*512 + jx*8];

  for (int st = 0; st < 64; st++){
    const int s0 = st*64;
    const short* kp = kgp + (size_t)s0*512;

    // ---- phase 1: S-tile = Q(h) . K(sc)^T, K streamed from L2 ----
    f32x4 sa = {0.f,0.f,0.f,0.f};
    {
      short8 kfA[8];
      #pragma unroll
      for (int j = 0; j < 8; j++) kfA[j] = *(const short8*)(kp + j*32);
      __builtin_amdgcn_sched_barrier(0);
      __builtin_amdgcn_s_setprio(1);
      #pragma unroll
      for (int kk = 0; kk < 8; kk++){
        short8 qf = *(const short8*)(qp0 + ((kk ^ kx) << 5));
        sa = mfma16(qf, kfA[kk], sa);
      }
      __builtin_amdgcn_s_setprio(0);
    }
    {
      short8 kfB[8];
      #pragma unroll
      for (int j = 0; j < 8; j++) kfB[j] = *(const short8*)(kp + 256 + j*32);
      __builtin_amdgcn_sched_barrier(0);
      __builtin_amdgcn_s_setprio(1);
      #pragma unroll
      for (int kk = 8; kk < 16; kk++){
        short8 qf = *(const short8*)(qp0 + ((kk ^ kx) << 5));
        sa = mfma16(qf, kfB[kk - 8], sa);
      }
      __builtin_amdgcn_s_setprio(0);
    }

    // ---- V batch 0 issued here: latency hides under exp + barrier ----
    short8 v0[8];
    #pragma unroll
    for (int dc = 0; dc < 8; dc++)
      v0[dc] = *(const short8*)(vbp + (size_t)dc*16*BT_ + s0);
    __builtin_amdgcn_sched_barrier(0);

    // ---- exp + P write + row-sum accum ----
    #pragma unroll
    for (int rg = 0; rg < 4; rg++){
      float e = __expf(sa[rg]);
      lacc[rg] += e;
      Pl[h][(l>>4)*4 + rg][sc*16 + (l&15)] = f2bf(e);
    }

    // mid barrier: P visible to all; no vmcnt coupling
    asm volatile("s_waitcnt lgkmcnt(0)" ::: "memory");
    __builtin_amdgcn_s_barrier();

    // ---- phase 2, ks=0 ----
    {
      short8 pa0 = *(const short8*)&Pl[0][l&15][(l>>4)*8];
      short8 pa1 = *(const short8*)&Pl[1][l&15][(l>>4)*8];
      __builtin_amdgcn_s_setprio(1);
      #pragma unroll
      for (int dc = 0; dc < 8; dc++){
        acc[0][dc] = mfma16(pa0, v0[dc], acc[0][dc]);
        acc[1][dc] = mfma16(pa1, v0[dc], acc[1][dc]);
      }
      __builtin_amdgcn_s_setprio(0);
    }
    // ---- phase 2, ks=1 (v1 issued after v0 dies: reg peak capped) ----
    {
      short8 v1[8];
      #pragma unroll
      for (int dc = 0; dc < 8; dc++)
        v1[dc] = *(const short8*)(vbp + (size_t)dc*16*BT_ + s0 + 32);
      short8 pa0 = *(const short8*)&Pl[0][l&15][32 + (l>>4)*8];
      short8 pa1 = *(const short8*)&Pl[1][l&15][32 + (l>>4)*8];
      __builtin_amdgcn_sched_barrier(0);
      __builtin_amdgcn_s_setprio(1);
      #pragma unroll
      for (int dc = 0; dc < 8; dc++){
        acc[0][dc] = mfma16(pa0, v1[dc], acc[0][dc]);
        acc[1][dc] = mfma16(pa1, v1[dc], acc[1][dc]);
      }
      __builtin_amdgcn_s_setprio(0);
    }

    // end barrier: P reads drained before next-iter P writes
    asm volatile("s_waitcnt lgkmcnt(0)" ::: "memory");
    __builtin_amdgcn_s_barrier();
  }

  // ---- lambda (post-loop) ----
  float s1 = 0.f, s2 = 0.f;
  #pragma unroll
  for (int i = 0; i < 8; i++){
    int idx = l*8 + i;
    s1 += lq1[idx]*lk1[idx];
    s2 += lq2[idx]*lk2[idx];
  }
  #pragma unroll
  for (int off = 1; off < 64; off <<= 1){
    s1 += __shfl_xor(s1, off, 64);
    s2 += __shfl_xor(s2, off, 64);
  }
  const float lam = __expf(s1) - __expf(s2) + LAMBDA_INIT_F;

  // ---- row sums -> 1/l per head ----
  #pragma unroll
  for (int off = 1; off < 16; off <<= 1)
    #pragma unroll
    for (int rg = 0; rg < 4; rg++) lacc[rg] += __shfl_xor(lacc[rg], off, 16);
  if ((l & 15) == 0){
    #pragma unroll
    for (int rg = 0; rg < 4; rg++) lsum[w][(l>>4)*4 + rg] = lacc[rg];
  }
  __syncthreads();
  if (tid < 32){
    int hh = tid >> 4, r = tid & 15;
    rinv[hh][r] = 1.0f / (lsum[hh][r] + lsum[hh+2][r] + lsum[hh+4][r] + lsum[hh+6][r]);
  }
  __syncthreads();

  // ---- RMSNorm pass 1: row sum-of-squares ----
  float ps[4] = {0.f,0.f,0.f,0.f};
  #pragma unroll
  for (int dc = 0; dc < 8; dc++){
    #pragma unroll
    for (int rg = 0; rg < 4; rg++){
      int t16 = (l>>4)*4 + rg;
      float o = acc[0][dc][rg]*rinv[0][t16] - lam*acc[1][dc][rg]*rinv[1][t16];
      ps[rg] += o*o;
    }
  }
  #pragma unroll
  for (int off = 1; off < 16; off <<= 1)
    #pragma unroll
    for (int rg = 0; rg < 4; rg++) ps[rg] += __shfl_xor(ps[rg], off, 16);
  if ((l & 15) == 0){
    #pragma unroll
    for (int rg = 0; rg < 4; rg++) ssq[w][(l>>4)*4 + rg] = ps[rg];
  }
  __syncthreads();

  // ---- RMSNorm pass 2: normalize + store ----
  #pragma unroll
  for (int rg = 0; rg < 4; rg++){
    int t16 = (l>>4)*4 + rg;
    float tot = 0.f;
    #pragma unroll
    for (int w8 = 0; w8 < 8; w8++) tot += ssq[w8][t16];
    float scale = rsqrtf(tot*(1.0f/1024.0f) + 1e-5f) * ONE_MINUS_LI_F;
    short* orow = Ab + (size_t)(b*T_ + t0 + t16)*1024 + w*128 + (l&15);
    #pragma unroll
    for (int dc = 0; dc < 8; dc++){
      float o = acc[0][dc][rg]*rinv[0][t16] - lam*acc[1][dc][rg]*rinv[1][t16];
      orow[dc*16] = f2bf(o*scale);
    }
  }
}

// ---------------- launcher ----------------
extern "C" void kernel_launch(void* const* d_in, const int* in_sizes, int n_in,
                              void* d_out, int out_size, void* d_ws, size_t ws_size,
                              hipStream_t stream){
  const float* q   = (const float*)d_in[0];
  const float* k   = (const float*)d_in[1];
  const float* v   = (const float*)d_in[2];
  const float* Wq  = (const float*)d_in[3];
  const float* Wk  = (const float*)d_in[4];
  const float* Wv  = (const float*)d_in[5];
  const float* Wo  = (const float*)d_in[6];
  const float* lq1 = (const float*)d_in[7];
  const float* lk1 = (const float*)d_in[8];
  const float* lq2 = (const float*)d_in[9];
  const float* lk2 = (const float*)d_in[10];

  short* ws   = (short*)d_ws;
  short* qb   = ws;                              // [8192][1024]
  short* kb   = qb  + (size_t)8192*1024;         // [8192][1024]
  short* vb   = kb  + (size_t)8192*1024;         // [8192][1024]
  short* Wqb  = vb  + (size_t)8192*1024;         // [1024][1024]
  short* Wkb  = Wqb + (size_t)1024*1024;         // [512][1024]
  short* Wvb  = Wkb + (size_t)512*1024;          // [1024][1024]
  short* Wob  = Wvb + (size_t)1024*1024;         // [1024][1024]
  short* QPb  = Wob + (size_t)1024*1024;         // [8192][1024] scaled
  short* KPb  = QPb + (size_t)8192*1024;         // [8192][512]
  short* VPTb = KPb + (size_t)8192*512;          // [1024][8192]
  short* Ab   = qb;                              // alias: qb dead after projections

  CvtArgs ca;
  ca.src[0]=q;  ca.dst[0]=qb;  ca.n4[0]=(8192*1024)/4;
  ca.src[1]=k;  ca.dst[1]=kb;  ca.n4[1]=(8192*1024)/4;
  ca.src[2]=v;  ca.dst[2]=vb;  ca.n4[2]=(8192*1024)/4;
  ca.src[3]=Wq; ca.dst[3]=Wqb; ca.n4[3]=(1024*1024)/4;
  ca.src[4]=Wk; ca.dst[4]=Wkb; ca.n4[4]=(512*1024)/4;
  ca.src[5]=Wv; ca.dst[5]=Wvb; ca.n4[5]=(1024*1024)/4;
  ca.src[6]=Wo; ca.dst[6]=Wob; ca.n4[6]=(1024*1024)/4;
  ca.total4 = ca.n4[0]+ca.n4[1]+ca.n4[2]+ca.n4[3]+ca.n4[4]+ca.n4[5]+ca.n4[6];
  k_cvt<<<2048, 256, 0, stream>>>(ca);

  // QP = (q Wq^T)*SCALING : M=8192 N=1024
  k_gemm<1><<<dim3(64, 8), 256, 0, stream>>>(qb, Wqb, QPb, 1024);
  // KP = k Wk^T : M=8192 N=512
  k_gemm<0><<<dim3(64, 4), 256, 0, stream>>>(kb, Wkb, KPb, 512);
  // VPT = Wv v^T : M=1024(d) N=8192(b*s)  -> VPT[d][bs]
  k_gemm<0><<<dim3(8, 64), 256, 0, stream>>>(Wvb, vb, VPTb, 8192);
  // fused dual-softmax attention + RMSNorm -> Ab (bf16)
  k_attn<<<dim3(512), 512, 0, stream>>>(QPb, KPb, VPTb, lq1, lk1, lq2, lk2, Ab);
  // OUT = Ab Wo^T : M=8192 N=1024, fp32
  k_gemm<2><<<dim3(64, 8), 256, 0, stream>>>(Ab, Wob, d_out, 1024);
}

// Round 9
// 479.416 us; speedup vs baseline: 2.9760x; 2.9760x over previous
//
#include <hip/hip_runtime.h>
#include <stdint.h>
#include <stddef.h>

#define T_   4096
#define BT_  8192
#define SCALING_F      0.04419417382415922f
#define LAMBDA_INIT_F  0.7836057665316212f
#define ONE_MINUS_LI_F 0.2163942334683788f

typedef __attribute__((ext_vector_type(8))) short short8;
typedef __attribute__((ext_vector_type(4))) short short4v;
typedef __attribute__((ext_vector_type(4))) float f32x4;

__device__ __forceinline__ short f2bf(float f){
  uint32_t u = __float_as_uint(f);
  uint32_t r = (u + 0x7fffu + ((u >> 16) & 1u)) >> 16;   // RNE
  return (short)(uint16_t)r;
}

__device__ __forceinline__ f32x4 mfma16(short8 a, short8 b, f32x4 c){
  return __builtin_amdgcn_mfma_f32_16x16x32_bf16(a, b, c, 0, 0, 0);
}

__device__ __forceinline__ void stage16(short* lds, const short* g){
  __builtin_amdgcn_global_load_lds(
      (const __attribute__((address_space(1))) void*)g,
      (__attribute__((address_space(3))) void*)lds, 16, 0, 0);
}

// ---------------- merged fp32 -> bf16 convert (7 segments) ----------------
struct CvtArgs {
  const float* src[7];
  short*       dst[7];
  int          n4[7];     // float4 count per segment
  int          total4;
};

__global__ void k_cvt(CvtArgs a){
  int i  = blockIdx.x*blockDim.x + threadIdx.x;
  int st = gridDim.x*blockDim.x;
  for (; i < a.total4; i += st){
    int seg = 0, off = i;
    #pragma unroll
    for (int s = 0; s < 6; s++){
      if (off >= a.n4[seg]){ off -= a.n4[seg]; seg++; }
    }
    float4 v = ((const float4*)a.src[seg])[off];
    short4v o;
    o.x = f2bf(v.x); o.y = f2bf(v.y); o.z = f2bf(v.z); o.w = f2bf(v.w);
    ((short4v*)a.dst[seg])[off] = o;
  }
}

// ---------------- NT GEMM: C[m][n] = sum_k A[m][k]*B[n][k], K=1024 fixed ----
// EPI: 0 = bf16 out, 1 = bf16 out * SCALING, 2 = fp32 out
template<int EPI>
__global__ __launch_bounds__(256, 3) void k_gemm(const short* __restrict__ A,
                                                 const short* __restrict__ Bm,
                                                 void* __restrict__ Cp, int ldc){
  __shared__ short As[128*32];
  __shared__ short Bs[128*32];
  const int tid = threadIdx.x;
  const int w = tid >> 6, l = tid & 63;
  const int m0 = blockIdx.x * 128;
  const int n0 = blockIdx.y * 128;
  const int wr = w >> 1, wc = w & 1;

  f32x4 acc[4][4] = {};

  const short* gA = A  + (size_t)(m0 + w*32 + (l>>2))*1024 + (l&3)*8;
  const short* gB = Bm + (size_t)(n0 + w*32 + (l>>2))*1024 + (l&3)*8;

  for (int k0 = 0; k0 < 1024; k0 += 32){
    stage16(As + w*1024,       gA + k0);
    stage16(As + w*1024 + 512, gA + 16*1024 + k0);
    stage16(Bs + w*1024,       gB + k0);
    stage16(Bs + w*1024 + 512, gB + 16*1024 + k0);
    __syncthreads();
    short8 aF[4], bF[4];
    #pragma unroll
    for (int i = 0; i < 4; i++){
      aF[i] = *(const short8*)&As[(wr*64 + i*16 + (l&15))*32 + (l>>4)*8];
      bF[i] = *(const short8*)&Bs[(wc*64 + i*16 + (l&15))*32 + (l>>4)*8];
    }
    #pragma unroll
    for (int i = 0; i < 4; i++)
      #pragma unroll
      for (int j = 0; j < 4; j++)
        acc[i][j] = mfma16(aF[i], bF[j], acc[i][j]);
    __syncthreads();
  }

  #pragma unroll
  for (int i = 0; i < 4; i++){
    #pragma unroll
    for (int j = 0; j < 4; j++){
      const size_t r0 = (size_t)m0 + wr*64 + i*16 + (l>>4)*4;
      const size_t c  = (size_t)n0 + wc*64 + j*16 + (l&15);
      #pragma unroll
      for (int rg = 0; rg < 4; rg++){
        float v = acc[i][j][rg];
        if (EPI == 2){
          ((float*)Cp)[(r0+rg)*(size_t)ldc + c] = v;
        } else {
          if (EPI == 1) v *= SCALING_F;
          ((short*)Cp)[(r0+rg)*(size_t)ldc + c] = f2bf(v);
        }
      }
    }
  }
}

// ---------------- fused dual-softmax attention + RMSNorm (v9) --------------
// EXACT R3 structure (proven 356us): 8 waves/512thr, 2 waves/SIMD, Q in LDS
// (64KB swz), K single-buffer LDS (64KB swz) staged for st+1 during phase-2,
// V prefetched to regs at iter top. Changes vs R3: phase-1 accumulator split
// into even/odd partials (4 indep MFMA chains of depth 8 vs 2x16), lambda
// post-loop, setprio around MFMA clusters, merged cvt.
__global__ __launch_bounds__(512, 2) void k_attn(
    const short* __restrict__ QP, const short* __restrict__ KP,
    const short* __restrict__ VPT,
    const float* __restrict__ lq1, const float* __restrict__ lk1,
    const float* __restrict__ lq2, const float* __restrict__ lk2,
    short* __restrict__ Ab)
{
  __shared__ short Ks[64*512];     // 64 KB, phys16Bchunk = logical ^ (srow&7)
  __shared__ short Qs[32*1024];    // 64 KB, phys16Bchunk(within 512-half) = logical ^ (trow&7)
  __shared__ short Pl[2][32][72];  // exp(S), 9-chunk row stride
  __shared__ float lsum[8][16];
  __shared__ float rinv[2][32];
  __shared__ float ssq[8][32];

  // XCD-aware bijective swizzle (256 % 8 == 0)
  int wg = blockIdx.x;
  wg = (wg & 7)*32 + (wg >> 3);
  const int b  = wg >> 7;
  const int t0 = (wg & 127) * 32;

  const int tid = threadIdx.x;
  const int w = tid >> 6, l = tid & 63;

  // phase-1 role: (h, tch) x scb (s-col pair). phase-2 role: wave = 128-wide d-slice.
  const int rc = w >> 1, h = rc >> 1, tch = rc & 1, scb = w & 1;

  f32x4 acc[4][8] = {};                // [rc2 = h*2+tc][dc]
  float lacc[4] = {0.f,0.f,0.f,0.f};

  const short* kpb = KP  + (size_t)(b*T_)*512;
  const short* vbp = VPT + (size_t)(w*128 + (l&15))*BT_ + (size_t)b*T_ + (l>>4)*8;

  // swizzled-read lane constants
  const int jx = (l >> 4) ^ (l & 3);
  const int kx = (l >> 2) & 1;

  // ---- prologue: stage Q (whole tile) + K(0), swizzled sources ----
  {
    const short* qsrc = QP + (size_t)(b*T_ + t0)*1024;
    #pragma unroll
    for (int j = 0; j < 4; j++){
      int r = w*4 + j;
      #pragma unroll
      for (int h2 = 0; h2 < 2; h2++)
        stage16(&Qs[r*1024 + h2*512],
                qsrc + (size_t)r*1024 + (h2*64 + (l ^ (r & 7)))*8);
    }
    #pragma unroll
    for (int j = 0; j < 8; j++)
      stage16(&Ks[(w*8 + j)*512], kpb + (size_t)(w*8 + j)*512 + ((l ^ j)*8));
  }
  __syncthreads();

  const short* qp0 = &Qs[(tch*16 + (l&15))*1024 + h*512 + jx*8];
  const short* kp0 = &Ks[(scb*32 + (l&15))*512 + jx*8];
  const short* kp1 = kp0 + 16*512;

  for (int st = 0; st < 64; st++){
    const int s0 = st*64;

    // ---- V prefetch into registers (consumed in phase 2) ----
    short8 varr[16];
    #pragma unroll
    for (int dc = 0; dc < 8; dc++)
      #pragma unroll
      for (int ks = 0; ks < 2; ks++)
        varr[dc*2 + ks] = *(const short8*)(vbp + (size_t)dc*16*BT_ + s0 + ks*32);
    __builtin_amdgcn_sched_barrier(0);   // pin issue before QK^T

    // ---- phase 1: S = Q.K^T (Q,K from swizzled LDS), 4 indep chains ----
    f32x4 sa0e = {0.f,0.f,0.f,0.f}, sa0o = {0.f,0.f,0.f,0.f};
    f32x4 sa1e = {0.f,0.f,0.f,0.f}, sa1o = {0.f,0.f,0.f,0.f};
    __builtin_amdgcn_s_setprio(1);
    #pragma unroll
    for (int kk = 0; kk < 16; kk += 2){
      const int ko0 = ((kk ^ kx) << 5);
      const int ko1 = (((kk + 1) ^ kx) << 5);
      short8 qf0 = *(const short8*)(qp0 + ko0);
      short8 b00 = *(const short8*)(kp0 + ko0);
      short8 b10 = *(const short8*)(kp1 + ko0);
      sa0e = mfma16(qf0, b00, sa0e);
      sa1e = mfma16(qf0, b10, sa1e);
      short8 qf1 = *(const short8*)(qp0 + ko1);
      short8 b01 = *(const short8*)(kp0 + ko1);
      short8 b11 = *(const short8*)(kp1 + ko1);
      sa0o = mfma16(qf1, b01, sa0o);
      sa1o = mfma16(qf1, b11, sa1o);
    }
    __builtin_amdgcn_s_setprio(0);
    f32x4 sa0 = sa0e + sa0o;
    f32x4 sa1 = sa1e + sa1o;

    // ---- exp + P write ----
    #pragma unroll
    for (int rg = 0; rg < 4; rg++){
      float e0 = __expf(sa0[rg]);
      float e1 = __expf(sa1[rg]);
      lacc[rg] += e0 + e1;
      int row = tch*16 + (l>>4)*4 + rg;
      Pl[h][row][(2*scb+0)*16 + (l&15)] = f2bf(e0);
      Pl[h][row][(2*scb+1)*16 + (l&15)] = f2bf(e1);
    }

    // mid barrier: own LDS ops drained; vmcnt untouched (V loads may still fly)
    asm volatile("s_waitcnt lgkmcnt(0)" ::: "memory");
    __builtin_amdgcn_s_barrier();

    // ---- phase 2: issue K(st+1) DMA, then P.V from registers ----
    if (st + 1 < 64){
      const short* ksrc = kpb + (size_t)((st+1)*64 + w*8)*512;
      #pragma unroll
      for (int j = 0; j < 8; j++)
        stage16(&Ks[(w*8 + j)*512], ksrc + (size_t)j*512 + ((l ^ j)*8));
    }

    #pragma unroll
    for (int ks = 0; ks < 2; ks++){
      short8 pa[4];
      #pragma unroll
      for (int rc2 = 0; rc2 < 4; rc2++)
        pa[rc2] = *(const short8*)&Pl[rc2>>1][(rc2&1)*16 + (l&15)][ks*32 + (l>>4)*8];
      __builtin_amdgcn_s_setprio(1);
      #pragma unroll
      for (int dc = 0; dc < 8; dc++)
        #pragma unroll
        for (int rc2 = 0; rc2 < 4; rc2++)
          acc[rc2][dc] = mfma16(pa[rc2], varr[dc*2 + ks], acc[rc2][dc]);
      __builtin_amdgcn_s_setprio(0);
    }

    __syncthreads();   // drains vmcnt(0): K(st+1) landed; lgkm: P reads done
  }

  // ---- lambda (post-loop) ----
  float s1 = 0.f, s2 = 0.f;
  #pragma unroll
  for (int i = 0; i < 8; i++){
    int idx = l*8 + i;
    s1 += lq1[idx]*lk1[idx];
    s2 += lq2[idx]*lk2[idx];
  }
  #pragma unroll
  for (int off = 1; off < 64; off <<= 1){
    s1 += __shfl_xor(s1, off, 64);
    s2 += __shfl_xor(s2, off, 64);
  }
  const float lam = __expf(s1) - __expf(s2) + LAMBDA_INIT_F;

  // ---- row sums -> 1/l ----
  #pragma unroll
  for (int off = 1; off < 16; off <<= 1)
    #pragma unroll
    for (int rg = 0; rg < 4; rg++) lacc[rg] += __shfl_xor(lacc[rg], off, 16);
  if ((l & 15) == 0){
    #pragma unroll
    for (int rg = 0; rg < 4; rg++) lsum[w][(l>>4)*4 + rg] = lacc[rg];
  }
  __syncthreads();
  if (tid < 64){
    int hh = tid >> 5, t = tid & 31;
    int rcc = hh*2 + (t >> 4), ric = t & 15;
    rinv[hh][t] = 1.0f / (lsum[rcc*2][ric] + lsum[rcc*2+1][ric]);
  }
  __syncthreads();

  // ---- combine pass 1: row sum-of-squares ----
  float ps[2][4] = {};
  #pragma unroll
  for (int tc = 0; tc < 2; tc++){
    #pragma unroll
    for (int dc = 0; dc < 8; dc++){
      #pragma unroll
      for (int rg = 0; rg < 4; rg++){
        int t32 = tc*16 + (l>>4)*4 + rg;
        float o = acc[tc][dc][rg]*rinv[0][t32] - lam*acc[2+tc][dc][rg]*rinv[1][t32];
        ps[tc][rg] += o*o;
      }
    }
  }
  #pragma unroll
  for (int tc = 0; tc < 2; tc++)
    #pragma unroll
    for (int off = 1; off < 16; off <<= 1)
      #pragma unroll
      for (int rg = 0; rg < 4; rg++) ps[tc][rg] += __shfl_xor(ps[tc][rg], off, 16);
  if ((l & 15) == 0){
    #pragma unroll
    for (int tc = 0; tc < 2; tc++)
      #pragma unroll
      for (int rg = 0; rg < 4; rg++) ssq[w][tc*16 + (l>>4)*4 + rg] = ps[tc][rg];
  }
  __syncthreads();

  // ---- combine pass 2: normalize + store ----
  #pragma unroll
  for (int tc = 0; tc < 2; tc++){
    #pragma unroll
    for (int rg = 0; rg < 4; rg++){
      int t32 = tc*16 + (l>>4)*4 + rg;
      float tot = 0.f;
      #pragma unroll
      for (int w8 = 0; w8 < 8; w8++) tot += ssq[w8][t32];
      float scale = rsqrtf(tot*(1.0f/1024.0f) + 1e-5f) * ONE_MINUS_LI_F;
      short* orow = Ab + (size_t)(b*T_ + t0 + t32)*1024 + w*128 + (l&15);
      #pragma unroll
      for (int dc = 0; dc < 8; dc++){
        float o = acc[tc][dc][rg]*rinv[0][t32] - lam*acc[2+tc][dc][rg]*rinv[1][t32];
        orow[dc*16] = f2bf(o*scale);
      }
    }
  }
}

// ---------------- launcher ----------------
extern "C" void kernel_launch(void* const* d_in, const int* in_sizes, int n_in,
                              void* d_out, int out_size, void* d_ws, size_t ws_size,
                              hipStream_t stream){
  const float* q   = (const float*)d_in[0];
  const float* k   = (const float*)d_in[1];
  const float* v   = (const float*)d_in[2];
  const float* Wq  = (const float*)d_in[3];
  const float* Wk  = (const float*)d_in[4];
  const float* Wv  = (const float*)d_in[5];
  const float* Wo  = (const float*)d_in[6];
  const float* lq1 = (const float*)d_in[7];
  const float* lk1 = (const float*)d_in[8];
  const float* lq2 = (const float*)d_in[9];
  const float* lk2 = (const float*)d_in[10];

  short* ws   = (short*)d_ws;
  short* qb   = ws;                              // [8192][1024]
  short* kb   = qb  + (size_t)8192*1024;         // [8192][1024]
  short* vb   = kb  + (size_t)8192*1024;         // [8192][1024]
  short* Wqb  = vb  + (size_t)8192*1024;         // [1024][1024]
  short* Wkb  = Wqb + (size_t)1024*1024;         // [512][1024]
  short* Wvb  = Wkb + (size_t)512*1024;          // [1024][1024]
  short* Wob  = Wvb + (size_t)1024*1024;         // [1024][1024]
  short* QPb  = Wob + (size_t)1024*1024;         // [8192][1024] scaled
  short* KPb  = QPb + (size_t)8192*1024;         // [8192][512]
  short* VPTb = KPb + (size_t)8192*512;          // [1024][8192]
  short* Ab   = qb;                              // alias: qb dead after projections

  CvtArgs ca;
  ca.src[0]=q;  ca.dst[0]=qb;  ca.n4[0]=(8192*1024)/4;
  ca.src[1]=k;  ca.dst[1]=kb;  ca.n4[1]=(8192*1024)/4;
  ca.src[2]=v;  ca.dst[2]=vb;  ca.n4[2]=(8192*1024)/4;
  ca.src[3]=Wq; ca.dst[3]=Wqb; ca.n4[3]=(1024*1024)/4;
  ca.src[4]=Wk; ca.dst[4]=Wkb; ca.n4[4]=(512*1024)/4;
  ca.src[5]=Wv; ca.dst[5]=Wvb; ca.n4[5]=(1024*1024)/4;
  ca.src[6]=Wo; ca.dst[6]=Wob; ca.n4[6]=(1024*1024)/4;
  ca.total4 = ca.n4[0]+ca.n4[1]+ca.n4[2]+ca.n4[3]+ca.n4[4]+ca.n4[5]+ca.n4[6];
  k_cvt<<<2048, 256, 0, stream>>>(ca);

  // QP = (q Wq^T)*SCALING : M=8192 N=1024
  k_gemm<1><<<dim3(64, 8), 256, 0, stream>>>(qb, Wqb, QPb, 1024);
  // KP = k Wk^T : M=8192 N=512
  k_gemm<0><<<dim3(64, 4), 256, 0, stream>>>(kb, Wkb, KPb, 512);
  // VPT = Wv v^T : M=1024(d) N=8192(b*s)  -> VPT[d][bs]
  k_gemm<0><<<dim3(8, 64), 256, 0, stream>>>(Wvb, vb, VPTb, 8192);
  // fused dual-softmax attention + RMSNorm -> Ab (bf16)
  k_attn<<<dim3(256), 512, 0, stream>>>(QPb, KPb, VPTb, lq1, lk1, lq2, lk2, Ab);
  // OUT = Ab Wo^T : M=8192 N=1024, fp32
  k_gemm<2><<<dim3(64, 8), 256, 0, stream>>>(Ab, Wob, d_out, 1024);
}